// Round 5
// baseline (13824.730 us; speedup 1.0000x reference)
//
#include <hip/hip_runtime.h>
#include <math.h>

// 4-layer tanh RNN (H=2048, T=512) + FC on last timestep.
// Round-5: round-4 compute core, HANDSHAKE REDESIGNED.
//  - r4 failure mode: 2048 waves spin-polling 32B/lane of h-data at s_sleep(1)
//    flooded the MALL (~tens of TB/s of demanded coherent reads) -> producer
//    stores + detect reads queued -> 17us/handshake.
//  - Fix: detect via dense per-block progress array prog[4][64] (one int per
//    producer block). Wave w polls ONLY the 8 own-layer + 8 prev-layer blocks
//    owning its column slice: one predicated 4B load on 16 lanes per iter,
//    s_sleep(4) backoff. Detect traffic drops ~30x. Data fetched once after
//    detect (agent loads). No sentinels needed; prog gates validity.
//  - Producer: wave0 stores 32 h values (128B), then lane0 RELEASE-stores
//    prog[l][gb]=t+1 (release drains the wave's prior vmem stores).
//  - Race-freedom of partial[t&1]: prog_A>=t+2 => A passed step-t+1 combine
//    barrier => all A's waves passed step-t+1 polls; union of all waves'
//    8-block sets = all 64 blocks => own block's prog>=t+1 => own wave0
//    finished reading partial[t&1] at step t. (8 waves x 8 blocks = 64.)
//  - Everything else as r4: 256 blocks x 512 thr (1/CU), layer=blk>>6,
//    32 rows/block, f16-packed weights + v_dot2_f32_f16 (no spill, proven),
//    distributed halving reduce, ONE barrier/step, fp32 bias+tanh finalize.

#define HH 2048
#define TT 512
#define NBLK 256
#define LBLK 64       // blocks per layer
#define ROWS 32       // rows per block
#define NTH 512

typedef unsigned long long u64;
typedef unsigned int u32;
typedef _Float16 h2 __attribute__((ext_vector_type(2)));

#if defined(__has_builtin)
#if __has_builtin(__builtin_amdgcn_fdot2)
#define HAS_FDOT2 1
#endif
#endif

__device__ __forceinline__ u64 ld_a8(const float* p) {
  return __hip_atomic_load((const u64*)p, __ATOMIC_RELAXED,
                           __HIP_MEMORY_SCOPE_AGENT);
}
__device__ __forceinline__ void st_a4(float* p, float v) {
  __hip_atomic_store(p, v, __ATOMIC_RELAXED, __HIP_MEMORY_SCOPE_AGENT);
}
__device__ __forceinline__ int ld_prog(const int* p) {
  return __hip_atomic_load(p, __ATOMIC_RELAXED, __HIP_MEMORY_SCOPE_AGENT);
}
__device__ __forceinline__ void st_prog(int* p, int v) {
  __hip_atomic_store(p, v, __ATOMIC_RELEASE, __HIP_MEMORY_SCOPE_AGENT);
}
__device__ __forceinline__ h2 pk2(float a, float b) {
  h2 r; r[0] = (_Float16)a; r[1] = (_Float16)b; return r;   // RNE converts
}
__device__ __forceinline__ float dot2(h2 a, h2 b, float c) {
#ifdef HAS_FDOT2
  return __builtin_amdgcn_fdot2(a, b, c, false);
#else
  return c + (float)a[0] * (float)b[0] + (float)a[1] * (float)b[1];
#endif
}
__device__ __forceinline__ float fast_tanh(float s) {
  float e = __expf(2.f * s);          // inf for large s -> 1; 0 -> -1
  return 1.f - 2.f / (e + 1.f);
}

__launch_bounds__(NTH, 2)
__global__ void rnn_d4(const float* __restrict__ x,
                       const float* __restrict__ w_ih,
                       const float* __restrict__ w_hh,
                       const float* __restrict__ b_ih,
                       const float* __restrict__ b_hh,
                       const float* __restrict__ w_fc,
                       const float* __restrict__ b_fc,
                       float* __restrict__ out,
                       float* ws)
{
  const int blk  = blockIdx.x;
  const int l    = blk >> 6;          // layer 0..3
  const int gb   = blk & (LBLK - 1);  // block within layer
  const int tid  = threadIdx.x;
  const int wid  = tid >> 6;
  const int lane = tid & 63;
  const int scol = wid * 256 + lane * 4;   // this lane's 4 columns
  const int pset = wid * 8 + (lane & 7);   // producer block this lane watches

  float* outB      = ws + (size_t)l * (TT + 1) * HH;
  const float* inB = ws + (size_t)(l - 1) * (TT + 1) * HH;  // l>0 only
  int* prog  = (int*)(ws + (size_t)4 * (TT + 1) * HH);      // [4][64]
  int* progO = prog + l * LBLK;
  int* progP = prog + (l - 1) * LBLK;                       // l>0 only

  __shared__ float partial[2][8][32];

  // ---- weights into VGPRs (once), f16-packed: [32][2] half2 each ----
  h2 whh[ROWS][2], wih[ROWS][2];
#pragma unroll
  for (int r = 0; r < ROWS; ++r) {
    const size_t rowoff = ((size_t)l * HH + gb * ROWS + r) * HH + scol;
    const float4 vh = *(const float4*)(w_hh + rowoff);
    whh[r][0] = pk2(vh.x, vh.y); whh[r][1] = pk2(vh.z, vh.w);
    const float4 vi = *(const float4*)(w_ih + rowoff);
    wih[r][0] = pk2(vi.x, vi.y); wih[r][1] = pk2(vi.z, vi.w);
  }
  float fbias = 0.f;
  if (wid == 0 && lane < 32)
    fbias = b_ih[l * HH + gb * ROWS + lane] + b_hh[l * HH + gb * ROWS + lane];

  // row this lane owns after the distributed reduce: bitrev5(lane&31)
  const int rrow = ((lane & 1) << 4) | ((lane & 2) << 2) | (lane & 4) |
                   ((lane & 8) >> 2) | ((lane & 16) >> 4);

  const float* po = outB + scol;            // own slot t (starts at t=0)
  const float* pp = inB + HH + scol;        // prev slot t+1
  float* ps = outB + HH + gb * ROWS + lane; // wave0 store ptr (slot t+1)
  const float* xb = x + (size_t)scol * TT;  // x[scol][t]

  for (int t = 0; t < TT; ++t) {
    // hoisted x gather (layer 0 only) — t-contiguous per lane, L1-friendly
    float xg0 = 0.f, xg1 = 0.f, xg2 = 0.f, xg3 = 0.f;
    if (l == 0) {
      xg0 = xb[0 * TT + t]; xg1 = xb[1 * TT + t];
      xg2 = xb[2 * TT + t]; xg3 = xb[3 * TT + t];
    }

    // ---- progress poll: own layer >= t (h slot t), prev layer >= t+1 ----
    for (;;) {
      bool ok = true;
      if (lane < 8)                 ok = ld_prog(progO + pset) >= t;
      else if (l > 0 && lane < 16)  ok = ld_prog(progP + pset) >= t + 1;
      if (__all(ok)) break;
      __builtin_amdgcn_s_sleep(4);
    }
    __builtin_amdgcn_sched_barrier(0);

    // ---- fetch (uncontended now): own h_{t-1} slice + prev h_t slice ----
    u64 o0 = ld_a8(po), o1 = ld_a8(po + 2), p0 = 0, p1 = 0;
    if (l > 0) { p0 = ld_a8(pp); p1 = ld_a8(pp + 2); }
    float hh0 = __uint_as_float((u32)o0), hh1 = __uint_as_float((u32)(o0 >> 32));
    float hh2 = __uint_as_float((u32)o1), hh3 = __uint_as_float((u32)(o1 >> 32));
    float hi0, hi1, hi2, hi3;
    if (l == 0) { hi0 = xg0; hi1 = xg1; hi2 = xg2; hi3 = xg3; }
    else {
      hi0 = __uint_as_float((u32)p0); hi1 = __uint_as_float((u32)(p0 >> 32));
      hi2 = __uint_as_float((u32)p1); hi3 = __uint_as_float((u32)(p1 >> 32));
    }
    const h2 ph0 = pk2(hh0, hh1), ph1 = pk2(hh2, hh3);
    const h2 pi0 = pk2(hi0, hi1), pi1 = pk2(hi2, hi3);

    // ---- per-lane partials: 32 rows x 4 cols, 4 fdot2/row ----
    float acc[ROWS];
#pragma unroll
    for (int r = 0; r < ROWS; ++r)
      acc[r] = dot2(whh[r][1], ph1,
               dot2(whh[r][0], ph0,
               dot2(wih[r][1], pi1,
               dot2(wih[r][0], pi0, 0.f))));

    // ---- distributed reduce: xor-32 pre-level, then 5 halving levels ----
#pragma unroll
    for (int i = 0; i < 32; ++i) acc[i] += __shfl_xor(acc[i], 32, 64);
#pragma unroll
    for (int lv = 0; lv < 5; ++lv) {
      const int m = 1 << lv;
      const int n = 16 >> lv;          // 16,8,4,2,1
      const bool up = (lane & m) != 0;
#pragma unroll
      for (int i = 0; i < 16; ++i) {
        if (i < n) {
          float mine   = up ? acc[i + n] : acc[i];
          float theirs = __shfl_xor(up ? acc[i] : acc[i + n], m, 64);
          acc[i] = mine + theirs;
        }
      }
    }
    if (lane < 32) partial[t & 1][wid][rrow] = acc[0];
    __syncthreads();                    // the ONLY barrier per step

    if (wid == 0) {
      if (lane < 32) {
        float s = fbias;
#pragma unroll
        for (int w = 0; w < 8; ++w) s += partial[t & 1][w][lane];
        st_a4(ps, fast_tanh(s));
      }
      if (lane == 0) st_prog(progO + gb, t + 1);  // release: orders h stores
    }
    po += HH; pp += HH; ps += HH;
  }

  // ---- FC on h3[T-1]: layer-3 group only (weight regs are dead now) ----
  if (l == 3) {
    float wf[ROWS][4];
#pragma unroll
    for (int r = 0; r < ROWS; ++r) {
      const float4 v = *(const float4*)(w_fc + (size_t)(gb * ROWS + r) * HH + scol);
      wf[r][0] = v.x; wf[r][1] = v.y; wf[r][2] = v.z; wf[r][3] = v.w;
    }
    for (;;) {
      bool ok = true;
      if (lane < 8) ok = ld_prog(progO + pset) >= TT;
      if (__all(ok)) break;
      __builtin_amdgcn_s_sleep(4);
    }
    __builtin_amdgcn_sched_barrier(0);
    const float* ph = outB + (size_t)TT * HH + scol;
    u64 o0 = ld_a8(ph), o1 = ld_a8(ph + 2);
    float h0 = __uint_as_float((u32)o0), h1 = __uint_as_float((u32)(o0 >> 32));
    float h2v = __uint_as_float((u32)o1), h3 = __uint_as_float((u32)(o1 >> 32));

    float acc[ROWS];
#pragma unroll
    for (int r = 0; r < ROWS; ++r)
      acc[r] = wf[r][0] * h0 + wf[r][1] * h1 + wf[r][2] * h2v + wf[r][3] * h3;
#pragma unroll
    for (int i = 0; i < 32; ++i) acc[i] += __shfl_xor(acc[i], 32, 64);
#pragma unroll
    for (int lv = 0; lv < 5; ++lv) {
      const int m = 1 << lv;
      const int n = 16 >> lv;
      const bool up = (lane & m) != 0;
#pragma unroll
      for (int i = 0; i < 16; ++i) {
        if (i < n) {
          float mine   = up ? acc[i + n] : acc[i];
          float theirs = __shfl_xor(up ? acc[i] : acc[i + n], m, 64);
          acc[i] = mine + theirs;
        }
      }
    }
    if (lane < 32) partial[0][wid][rrow] = acc[0];
    __syncthreads();
    if (wid == 0 && lane < 32) {
      float s = b_fc[gb * ROWS + lane];
#pragma unroll
      for (int w = 0; w < 8; ++w) s += partial[0][w][lane];
      out[gb * ROWS + lane] = s;
    }
  }
}

extern "C" void kernel_launch(void* const* d_in, const int* in_sizes, int n_in,
                              void* d_out, int out_size, void* d_ws, size_t ws_size,
                              hipStream_t stream) {
  const float* x    = (const float*)d_in[0];
  const float* w_ih = (const float*)d_in[1];
  const float* w_hh = (const float*)d_in[2];
  const float* b_ih = (const float*)d_in[3];
  const float* b_hh = (const float*)d_in[4];
  const float* w_fc = (const float*)d_in[5];
  const float* b_fc = (const float*)d_in[6];
  float* out = (float*)d_out;
  float* ws  = (float*)d_ws;

  // 4 exchange buffers (TT+1)xHH floats each, then prog[4][64] ints.
  // Zero slot 0 (= h_{-1}) of each buffer and the prog array every launch.
  const size_t bufFloats = (size_t)(TT + 1) * HH;
  for (int l = 0; l < 4; ++l)
    hipMemsetAsync(ws + l * bufFloats, 0, HH * sizeof(float), stream);
  hipMemsetAsync(ws + 4 * bufFloats, 0, 4 * LBLK * sizeof(int), stream);

  rnn_d4<<<NBLK, NTH, 0, stream>>>(x, w_ih, w_hh, b_ih, b_hh,
                                   w_fc, b_fc, out, ws);
}

// Round 6
// 13285.187 us; speedup vs baseline: 1.0406x; 1.0406x over previous
//
#include <hip/hip_runtime.h>
#include <math.h>

// 4-layer tanh RNN (H=2048, T=512) + FC on last timestep.
// Round-6: r4 compute core + COUNTER-BASED handshake (no release atomics,
// no data-polling flood, minimal poll fan-in).
//  - r5 lesson: compiler-generated agent RELEASE fences + detect->fetch
//    serialization made steps slower (27us). r4 lesson: 32B/lane data-polling
//    floods the MALL (17us). r2 floor was 6.2us. New scheme polls ONE uniform
//    4B counter per dependency per wave (1 MALL request/wave/iter).
//  - cnt[l][t] (one-shot, t-indexed): producer block's wave0 stores its 32 h
//    values (relaxed agent atomics), manual `s_waitcnt vmcnt(0)` (release
//    without compiler fence baggage), then lane0 does a RELAXED
//    global_atomic_add(cnt[l][t+1], 1).
//  - Consumer wave: poll cnt[l][t]==64 (own h_{t-1}, skip at t=0) and
//    cnt[l-1][t+1]==64 (prev-layer h_t), all lanes same address (broadcast),
//    s_sleep(2) backoff; then fetch 16B/lane slices and compute.
//  - partial[t&1] LDS race-freedom: a wave writes partial[t&1] at step t only
//    after cnt[l][t]==64, which includes OWN block's add, which wave0 issues
//    after its step-(t-1) finalize, whose poll of cnt[l][t-1] transitively
//    orders the step-(t-2) read of partial[t&1]. Safe.
//  - Core unchanged from r4 (proven no-spill): 256 blocks x 512 thr (1/CU),
//    layer=blk>>6, 64 blocks/layer, 32 rows/block, f16-packed weights +
//    v_dot2_f32_f16, distributed halving reduce, ONE barrier/step, wave0
//    finalizes fp32 bias + tanh, publishes 32 rows.

#define HH 2048
#define TT 512
#define NBLK 256
#define LBLK 64       // blocks per layer
#define ROWS 32       // rows per block
#define NTH 512
#define CROW 513      // cnt row stride (entries 1..512 used)

typedef unsigned long long u64;
typedef unsigned int u32;
typedef _Float16 h2 __attribute__((ext_vector_type(2)));

#if defined(__has_builtin)
#if __has_builtin(__builtin_amdgcn_fdot2)
#define HAS_FDOT2 1
#endif
#endif

__device__ __forceinline__ u64 ld_a8(const float* p) {
  return __hip_atomic_load((const u64*)p, __ATOMIC_RELAXED,
                           __HIP_MEMORY_SCOPE_AGENT);
}
__device__ __forceinline__ void st_a4(float* p, float v) {
  __hip_atomic_store(p, v, __ATOMIC_RELAXED, __HIP_MEMORY_SCOPE_AGENT);
}
__device__ __forceinline__ int ld_cnt(const int* p) {
  return __hip_atomic_load(p, __ATOMIC_RELAXED, __HIP_MEMORY_SCOPE_AGENT);
}
__device__ __forceinline__ h2 pk2(float a, float b) {
  h2 r; r[0] = (_Float16)a; r[1] = (_Float16)b; return r;   // RNE converts
}
__device__ __forceinline__ float dot2(h2 a, h2 b, float c) {
#ifdef HAS_FDOT2
  return __builtin_amdgcn_fdot2(a, b, c, false);
#else
  return c + (float)a[0] * (float)b[0] + (float)a[1] * (float)b[1];
#endif
}
__device__ __forceinline__ float fast_tanh(float s) {
  float e = __expf(2.f * s);          // inf for large s -> 1; 0 -> -1
  return 1.f - 2.f / (e + 1.f);
}

__launch_bounds__(NTH, 2)
__global__ void rnn_d4(const float* __restrict__ x,
                       const float* __restrict__ w_ih,
                       const float* __restrict__ w_hh,
                       const float* __restrict__ b_ih,
                       const float* __restrict__ b_hh,
                       const float* __restrict__ w_fc,
                       const float* __restrict__ b_fc,
                       float* __restrict__ out,
                       float* ws)
{
  const int blk  = blockIdx.x;
  const int l    = blk >> 6;          // layer 0..3
  const int gb   = blk & (LBLK - 1);  // block within layer
  const int tid  = threadIdx.x;
  const int wid  = tid >> 6;
  const int lane = tid & 63;
  const int scol = wid * 256 + lane * 4;   // this lane's 4 columns

  float* outB      = ws + (size_t)l * (TT + 1) * HH;
  const float* inB = ws + (size_t)(l - 1) * (TT + 1) * HH;  // l>0 only
  int* cnt  = (int*)(ws + (size_t)4 * (TT + 1) * HH);       // [4][CROW]
  int* cO = cnt + l * CROW;
  const int* cP = cnt + (l - 1) * CROW;                     // l>0 only

  __shared__ float partial[2][8][32];

  // ---- weights into VGPRs (once), f16-packed: [32][2] half2 each ----
  h2 whh[ROWS][2], wih[ROWS][2];
#pragma unroll
  for (int r = 0; r < ROWS; ++r) {
    const size_t rowoff = ((size_t)l * HH + gb * ROWS + r) * HH + scol;
    const float4 vh = *(const float4*)(w_hh + rowoff);
    whh[r][0] = pk2(vh.x, vh.y); whh[r][1] = pk2(vh.z, vh.w);
    const float4 vi = *(const float4*)(w_ih + rowoff);
    wih[r][0] = pk2(vi.x, vi.y); wih[r][1] = pk2(vi.z, vi.w);
  }
  float fbias = 0.f;
  if (wid == 0 && lane < 32)
    fbias = b_ih[l * HH + gb * ROWS + lane] + b_hh[l * HH + gb * ROWS + lane];

  // row this lane owns after the distributed reduce: bitrev5(lane&31)
  const int rrow = ((lane & 1) << 4) | ((lane & 2) << 2) | (lane & 4) |
                   ((lane & 8) >> 2) | ((lane & 16) >> 4);

  const float* po = outB + scol;            // own slot t (starts at t=0)
  const float* pp = inB + HH + scol;        // prev slot t+1
  float* ps = outB + HH + gb * ROWS + lane; // wave0 store ptr (slot t+1)
  const float* xb = x + (size_t)scol * TT;  // x[scol][t]

  for (int t = 0; t < TT; ++t) {
    // hoisted x gather (layer 0 only) — latency hides under the poll
    float xg0 = 0.f, xg1 = 0.f, xg2 = 0.f, xg3 = 0.f;
    if (l == 0) {
      xg0 = xb[0 * TT + t]; xg1 = xb[1 * TT + t];
      xg2 = xb[2 * TT + t]; xg3 = xb[3 * TT + t];
    }

    // ---- counter poll: own cnt[l][t]==64 (skip t=0), prev cnt[l-1][t+1] ---
    if ((t > 0) | (l > 0)) {
      for (;;) {
        bool ok = true;
        if (t > 0) ok = (ld_cnt(cO + t) == LBLK);
        if (l > 0) ok = ok & (ld_cnt(cP + t + 1) == LBLK);
        if (ok) break;
        __builtin_amdgcn_s_sleep(2);
      }
    }
    __builtin_amdgcn_sched_barrier(0);

    // ---- fetch (uncontended): own h_{t-1} slice + prev h_t slice ----
    u64 o0 = ld_a8(po), o1 = ld_a8(po + 2), p0 = 0, p1 = 0;
    if (l > 0) { p0 = ld_a8(pp); p1 = ld_a8(pp + 2); }
    float hh0 = __uint_as_float((u32)o0), hh1 = __uint_as_float((u32)(o0 >> 32));
    float hh2 = __uint_as_float((u32)o1), hh3 = __uint_as_float((u32)(o1 >> 32));
    float hi0, hi1, hi2, hi3;
    if (l == 0) { hi0 = xg0; hi1 = xg1; hi2 = xg2; hi3 = xg3; }
    else {
      hi0 = __uint_as_float((u32)p0); hi1 = __uint_as_float((u32)(p0 >> 32));
      hi2 = __uint_as_float((u32)p1); hi3 = __uint_as_float((u32)(p1 >> 32));
    }
    const h2 ph0 = pk2(hh0, hh1), ph1 = pk2(hh2, hh3);
    const h2 pi0 = pk2(hi0, hi1), pi1 = pk2(hi2, hi3);

    // ---- per-lane partials: 32 rows x 4 cols, 4 fdot2/row ----
    float acc[ROWS];
#pragma unroll
    for (int r = 0; r < ROWS; ++r)
      acc[r] = dot2(whh[r][1], ph1,
               dot2(whh[r][0], ph0,
               dot2(wih[r][1], pi1,
               dot2(wih[r][0], pi0, 0.f))));

    // ---- distributed reduce: xor-32 pre-level, then 5 halving levels ----
#pragma unroll
    for (int i = 0; i < 32; ++i) acc[i] += __shfl_xor(acc[i], 32, 64);
#pragma unroll
    for (int lv = 0; lv < 5; ++lv) {
      const int m = 1 << lv;
      const int n = 16 >> lv;          // 16,8,4,2,1
      const bool up = (lane & m) != 0;
#pragma unroll
      for (int i = 0; i < 16; ++i) {
        if (i < n) {
          float mine   = up ? acc[i + n] : acc[i];
          float theirs = __shfl_xor(up ? acc[i] : acc[i + n], m, 64);
          acc[i] = mine + theirs;
        }
      }
    }
    if (lane < 32) partial[t & 1][wid][rrow] = acc[0];
    __syncthreads();                    // the ONLY barrier per step

    if (wid == 0) {
      if (lane < 32) {
        float s = fbias;
#pragma unroll
        for (int w = 0; w < 8; ++w) s += partial[t & 1][w][lane];
        st_a4(ps, fast_tanh(s));
      }
      // manual release: wait own stores visible at MALL, then relaxed add.
      asm volatile("s_waitcnt vmcnt(0)" ::: "memory");
      if (lane == 0)
        __hip_atomic_fetch_add(cO + (t + 1), 1, __ATOMIC_RELAXED,
                               __HIP_MEMORY_SCOPE_AGENT);
    }
    po += HH; pp += HH; ps += HH;
  }

  // ---- FC on h3[T-1]: layer-3 group only (weight regs are dead now) ----
  if (l == 3) {
    float wf[ROWS][4];
#pragma unroll
    for (int r = 0; r < ROWS; ++r) {
      const float4 v = *(const float4*)(w_fc + (size_t)(gb * ROWS + r) * HH + scol);
      wf[r][0] = v.x; wf[r][1] = v.y; wf[r][2] = v.z; wf[r][3] = v.w;
    }
    for (;;) {
      if (ld_cnt(cO + TT) == LBLK) break;
      __builtin_amdgcn_s_sleep(2);
    }
    __builtin_amdgcn_sched_barrier(0);
    const float* ph = outB + (size_t)TT * HH + scol;
    u64 o0 = ld_a8(ph), o1 = ld_a8(ph + 2);
    float h0 = __uint_as_float((u32)o0), h1 = __uint_as_float((u32)(o0 >> 32));
    float h2v = __uint_as_float((u32)o1), h3 = __uint_as_float((u32)(o1 >> 32));

    float acc[ROWS];
#pragma unroll
    for (int r = 0; r < ROWS; ++r)
      acc[r] = wf[r][0] * h0 + wf[r][1] * h1 + wf[r][2] * h2v + wf[r][3] * h3;
#pragma unroll
    for (int i = 0; i < 32; ++i) acc[i] += __shfl_xor(acc[i], 32, 64);
#pragma unroll
    for (int lv = 0; lv < 5; ++lv) {
      const int m = 1 << lv;
      const int n = 16 >> lv;
      const bool up = (lane & m) != 0;
#pragma unroll
      for (int i = 0; i < 16; ++i) {
        if (i < n) {
          float mine   = up ? acc[i + n] : acc[i];
          float theirs = __shfl_xor(up ? acc[i] : acc[i + n], m, 64);
          acc[i] = mine + theirs;
        }
      }
    }
    if (lane < 32) partial[0][wid][rrow] = acc[0];
    __syncthreads();
    if (wid == 0 && lane < 32) {
      float s = b_fc[gb * ROWS + lane];
#pragma unroll
      for (int w = 0; w < 8; ++w) s += partial[0][w][lane];
      out[gb * ROWS + lane] = s;
    }
  }
}

extern "C" void kernel_launch(void* const* d_in, const int* in_sizes, int n_in,
                              void* d_out, int out_size, void* d_ws, size_t ws_size,
                              hipStream_t stream) {
  const float* x    = (const float*)d_in[0];
  const float* w_ih = (const float*)d_in[1];
  const float* w_hh = (const float*)d_in[2];
  const float* b_ih = (const float*)d_in[3];
  const float* b_hh = (const float*)d_in[4];
  const float* w_fc = (const float*)d_in[5];
  const float* b_fc = (const float*)d_in[6];
  float* out = (float*)d_out;
  float* ws  = (float*)d_ws;

  // 4 exchange buffers (TT+1)xHH floats each, then cnt[4][CROW] ints.
  // Zero slot 0 (= h_{-1}) of each buffer and the cnt array every launch.
  const size_t bufFloats = (size_t)(TT + 1) * HH;
  for (int l = 0; l < 4; ++l)
    hipMemsetAsync(ws + l * bufFloats, 0, HH * sizeof(float), stream);
  hipMemsetAsync(ws + 4 * bufFloats, 0, 4 * CROW * sizeof(int), stream);

  rnn_d4<<<NBLK, NTH, 0, stream>>>(x, w_ih, w_hh, b_ih, b_hh,
                                   w_fc, b_fc, out, ws);
}

// Round 7
// 8929.273 us; speedup vs baseline: 1.5482x; 1.4878x over previous
//
#include <hip/hip_runtime.h>
#include <math.h>

// 4-layer tanh RNN (H=2048, T=512) + FC on last timestep.
// Round-7: depth-4 structure + r2's PROVEN rendezvous mechanics.
//  - Cross-round evidence: r2 (depth-2, sentinel data-as-flag, s_sleep(2),
//    poll->barrier->compute lockstep) = 6.2us/handshake. r4 (depth-4, same
//    sentinel scheme but s_sleep(1) and NO post-poll barrier) = 17us.
//    r5/r6 (detect-then-fetch schemes) = 26us. Hypothesis: the free-running
//    waves + 2x poll rate flood the coherence point during the critical
//    store->visibility window; the post-poll barrier re-lockstepps each
//    block so polls happen in phase and stop once per step.
//  - This round: r4 verbatim EXCEPT (1) s_sleep(1)->s_sleep(2),
//    (2) __syncthreads() between poll and compute (barrier1, as r2).
//  - Core (proven r4): 256 blocks x 512 thr (1/CU), layer=blk>>6, 64
//    blocks/layer, 32 rows/block, f16-packed weights + v_dot2_f32_f16
//    (VGPR=128, no spill), direct register feed poll->compute, distributed
//    halving reduce, partial[t&1] LDS, wave0 finalizes fp32 bias + tanh,
//    relaxed agent stores, data-as-flag (0xFFFFFFFF sentinel) handshake.

#define HH 2048
#define TT 512
#define NBLK 256
#define LBLK 64       // blocks per layer
#define ROWS 32       // rows per block
#define NTH 512

typedef unsigned long long u64;
typedef unsigned int u32;
typedef _Float16 h2 __attribute__((ext_vector_type(2)));

#if defined(__has_builtin)
#if __has_builtin(__builtin_amdgcn_fdot2)
#define HAS_FDOT2 1
#endif
#endif

__device__ __forceinline__ u64 ld_a8(const float* p) {
  return __hip_atomic_load((const u64*)p, __ATOMIC_RELAXED,
                           __HIP_MEMORY_SCOPE_AGENT);
}
__device__ __forceinline__ void st_a4(float* p, float v) {
  __hip_atomic_store(p, v, __ATOMIC_RELAXED, __HIP_MEMORY_SCOPE_AGENT);
}
__device__ __forceinline__ bool fresh8(u64 v) {
  return ((u32)v != 0xFFFFFFFFu) & ((u32)(v >> 32) != 0xFFFFFFFFu);
}
__device__ __forceinline__ h2 pk2(float a, float b) {
  h2 r; r[0] = (_Float16)a; r[1] = (_Float16)b; return r;   // RNE converts
}
__device__ __forceinline__ float dot2(h2 a, h2 b, float c) {
#ifdef HAS_FDOT2
  return __builtin_amdgcn_fdot2(a, b, c, false);
#else
  return c + (float)a[0] * (float)b[0] + (float)a[1] * (float)b[1];
#endif
}
__device__ __forceinline__ float fast_tanh(float s) {
  float e = __expf(2.f * s);          // inf for large s -> 1; 0 -> -1
  return 1.f - 2.f / (e + 1.f);
}

__launch_bounds__(NTH, 2)
__global__ void rnn_d4(const float* __restrict__ x,
                       const float* __restrict__ w_ih,
                       const float* __restrict__ w_hh,
                       const float* __restrict__ b_ih,
                       const float* __restrict__ b_hh,
                       const float* __restrict__ w_fc,
                       const float* __restrict__ b_fc,
                       float* __restrict__ out,
                       float* ws)
{
  const int blk  = blockIdx.x;
  const int l    = blk >> 6;          // layer 0..3
  const int gb   = blk & (LBLK - 1);  // block within layer
  const int tid  = threadIdx.x;
  const int wid  = tid >> 6;
  const int lane = tid & 63;
  const int scol = wid * 256 + lane * 4;   // this lane's 4 columns

  float* outB      = ws + (size_t)l * (TT + 1) * HH;
  const float* inB = ws + (size_t)(l - 1) * (TT + 1) * HH;  // l>0 only

  __shared__ float partial[2][8][32];

  // ---- weights into VGPRs (once), f16-packed: [32][2] half2 each ----
  h2 whh[ROWS][2], wih[ROWS][2];
#pragma unroll
  for (int r = 0; r < ROWS; ++r) {
    const size_t rowoff = ((size_t)l * HH + gb * ROWS + r) * HH + scol;
    const float4 vh = *(const float4*)(w_hh + rowoff);
    whh[r][0] = pk2(vh.x, vh.y); whh[r][1] = pk2(vh.z, vh.w);
    const float4 vi = *(const float4*)(w_ih + rowoff);
    wih[r][0] = pk2(vi.x, vi.y); wih[r][1] = pk2(vi.z, vi.w);
  }
  float fbias = 0.f;
  if (wid == 0 && lane < 32)
    fbias = b_ih[l * HH + gb * ROWS + lane] + b_hh[l * HH + gb * ROWS + lane];

  // row this lane owns after the distributed reduce: bitrev5(lane&31)
  const int rrow = ((lane & 1) << 4) | ((lane & 2) << 2) | (lane & 4) |
                   ((lane & 8) >> 2) | ((lane & 16) >> 4);

  const float* po = outB + scol;            // own slot t (starts at t=0)
  const float* pp = inB + HH + scol;        // prev slot t+1
  float* ps = outB + HH + gb * ROWS + lane; // wave0 store ptr (slot t+1)
  const float* xb = x + (size_t)scol * TT;  // x[scol][t]

  for (int t = 0; t < TT; ++t) {
    // hoisted x gather (layer 0 only) — latency hides under the poll
    float xg0 = 0.f, xg1 = 0.f, xg2 = 0.f, xg3 = 0.f;
    if (l == 0) {
      xg0 = xb[0 * TT + t]; xg1 = xb[1 * TT + t];
      xg2 = xb[2 * TT + t]; xg3 = xb[3 * TT + t];
    }

    // ---- sentinel poll: own h_{t-1} slice (+ prev-layer h_t slice) ----
    u64 o0, o1, p0 = 0, p1 = 0;
    for (;;) {
      o0 = ld_a8(po);
      o1 = ld_a8(po + 2);
      if (l > 0) { p0 = ld_a8(pp); p1 = ld_a8(pp + 2); }
      bool ok = fresh8(o0) & fresh8(o1);
      if (l > 0) ok = ok & fresh8(p0) & fresh8(p1);
      if (__all(ok)) break;
      __builtin_amdgcn_s_sleep(2);
    }
    __syncthreads();   // barrier1 (r2 lockstep): whole block leaves the poll
                       // phase together; no wave free-runs into the next
                       // step's poll while others still compute/store.

    float hh0 = __uint_as_float((u32)o0), hh1 = __uint_as_float((u32)(o0 >> 32));
    float hh2 = __uint_as_float((u32)o1), hh3 = __uint_as_float((u32)(o1 >> 32));
    float hi0, hi1, hi2, hi3;
    if (l == 0) { hi0 = xg0; hi1 = xg1; hi2 = xg2; hi3 = xg3; }
    else {
      hi0 = __uint_as_float((u32)p0); hi1 = __uint_as_float((u32)(p0 >> 32));
      hi2 = __uint_as_float((u32)p1); hi3 = __uint_as_float((u32)(p1 >> 32));
    }
    const h2 ph0 = pk2(hh0, hh1), ph1 = pk2(hh2, hh3);
    const h2 pi0 = pk2(hi0, hi1), pi1 = pk2(hi2, hi3);

    // ---- per-lane partials: 32 rows x 4 cols, 4 fdot2/row ----
    float acc[ROWS];
#pragma unroll
    for (int r = 0; r < ROWS; ++r)
      acc[r] = dot2(whh[r][1], ph1,
               dot2(whh[r][0], ph0,
               dot2(wih[r][1], pi1,
               dot2(wih[r][0], pi0, 0.f))));

    // ---- distributed reduce: xor-32 pre-level, then 5 halving levels ----
#pragma unroll
    for (int i = 0; i < 32; ++i) acc[i] += __shfl_xor(acc[i], 32, 64);
#pragma unroll
    for (int lv = 0; lv < 5; ++lv) {
      const int m = 1 << lv;
      const int n = 16 >> lv;          // 16,8,4,2,1
      const bool up = (lane & m) != 0;
#pragma unroll
      for (int i = 0; i < 16; ++i) {
        if (i < n) {
          float mine   = up ? acc[i + n] : acc[i];
          float theirs = __shfl_xor(up ? acc[i] : acc[i + n], m, 64);
          acc[i] = mine + theirs;
        }
      }
    }
    if (lane < 32) partial[t & 1][wid][rrow] = acc[0];
    __syncthreads();                    // barrier2: partials ready

    if (wid == 0 && lane < 32) {
      float s = fbias;
#pragma unroll
      for (int w = 0; w < 8; ++w) s += partial[t & 1][w][lane];
      st_a4(ps, fast_tanh(s));
    }
    po += HH; pp += HH; ps += HH;
    // Other waves re-enter the next poll now; the wave whose slice covers
    // our own 32 rows gates barrier1(t+1) on our store, so partial[] and
    // LDS reuse stay ordered exactly as in r2.
  }

  // ---- FC on h3[T-1]: layer-3 group only (weight regs are dead now) ----
  if (l == 3) {
    float wf[ROWS][4];
#pragma unroll
    for (int r = 0; r < ROWS; ++r) {
      const float4 v = *(const float4*)(w_fc + (size_t)(gb * ROWS + r) * HH + scol);
      wf[r][0] = v.x; wf[r][1] = v.y; wf[r][2] = v.z; wf[r][3] = v.w;
    }
    const float* ph = outB + (size_t)TT * HH + scol;
    u64 o0, o1;
    for (;;) {
      o0 = ld_a8(ph);
      o1 = ld_a8(ph + 2);
      if (__all(fresh8(o0) & fresh8(o1))) break;
      __builtin_amdgcn_s_sleep(2);
    }
    float h0 = __uint_as_float((u32)o0), h1 = __uint_as_float((u32)(o0 >> 32));
    float h2v = __uint_as_float((u32)o1), h3 = __uint_as_float((u32)(o1 >> 32));

    float acc[ROWS];
#pragma unroll
    for (int r = 0; r < ROWS; ++r)
      acc[r] = wf[r][0] * h0 + wf[r][1] * h1 + wf[r][2] * h2v + wf[r][3] * h3;
#pragma unroll
    for (int i = 0; i < 32; ++i) acc[i] += __shfl_xor(acc[i], 32, 64);
#pragma unroll
    for (int lv = 0; lv < 5; ++lv) {
      const int m = 1 << lv;
      const int n = 16 >> lv;
      const bool up = (lane & m) != 0;
#pragma unroll
      for (int i = 0; i < 16; ++i) {
        if (i < n) {
          float mine   = up ? acc[i + n] : acc[i];
          float theirs = __shfl_xor(up ? acc[i] : acc[i + n], m, 64);
          acc[i] = mine + theirs;
        }
      }
    }
    if (lane < 32) partial[0][wid][rrow] = acc[0];
    __syncthreads();
    if (wid == 0 && lane < 32) {
      float s = b_fc[gb * ROWS + lane];
#pragma unroll
      for (int w = 0; w < 8; ++w) s += partial[0][w][lane];
      out[gb * ROWS + lane] = s;
    }
  }
}

extern "C" void kernel_launch(void* const* d_in, const int* in_sizes, int n_in,
                              void* d_out, int out_size, void* d_ws, size_t ws_size,
                              hipStream_t stream) {
  const float* x    = (const float*)d_in[0];
  const float* w_ih = (const float*)d_in[1];
  const float* w_hh = (const float*)d_in[2];
  const float* b_ih = (const float*)d_in[3];
  const float* b_hh = (const float*)d_in[4];
  const float* w_fc = (const float*)d_in[5];
  const float* b_fc = (const float*)d_in[6];
  float* out = (float*)d_out;
  float* ws  = (float*)d_ws;

  // 4 exchange buffers (one per layer): (TT+1) x HH floats each.
  // Sentinel-fill, then zero slot 0 (= h_{-1}) of each.
  const size_t bufFloats = (size_t)(TT + 1) * HH;
  hipMemsetAsync(ws, 0xFF, 4 * bufFloats * sizeof(float), stream);
  for (int l = 0; l < 4; ++l)
    hipMemsetAsync(ws + l * bufFloats, 0, HH * sizeof(float), stream);

  rnn_d4<<<NBLK, NTH, 0, stream>>>(x, w_ih, w_hh, b_ih, b_hh,
                                   w_fc, b_fc, out, ws);
}

// Round 8
// 8660.957 us; speedup vs baseline: 1.5962x; 1.0310x over previous
//
#include <hip/hip_runtime.h>
#include <math.h>

// 4-layer tanh RNN (H=2048, T=512) + FC on last timestep.
// Round-8: r7 base, POLL TRAFFIC CUT ~8x. Discriminating experiment for the
// fabric-congestion theory of the depth-4 cadence regression (17us vs r2's
// 6.2us):
//  - r7 demands ~25 TB/s of agent-scope MALL poll reads (7 polled buffer
//    streams x 2048 waves x 2-4 x 512B loads every ~128ns). Theory: this
//    saturates the coherence fabric, inflating every RT including the
//    critical producer-store -> consumer-detect path.
//  - Change 1: s_sleep(2) -> s_sleep(8) (poll sampling ~0.3-0.5us period).
//  - Change 2: split poll — own-layer slice first (usually fresh: produced a
//    full step ago; exits in ~1 iter, regs retained), THEN camp on the
//    prev-layer slice only. Steady-state traffic ~halves again.
//  - Everything else BYTE-IDENTICAL to r7: 256 blocks x 512 thr (1/CU),
//    layer=blk>>6, 64 blocks/layer, 32 rows/block, f16-packed weights +
//    v_dot2_f32_f16 (VGPR=128, no spill), data-as-flag sentinel handshake,
//    post-poll lockstep barrier, distributed halving reduce, partial[t&1],
//    wave0 fp32 bias + tanh finalize, relaxed agent stores.

#define HH 2048
#define TT 512
#define NBLK 256
#define LBLK 64       // blocks per layer
#define ROWS 32       // rows per block
#define NTH 512

typedef unsigned long long u64;
typedef unsigned int u32;
typedef _Float16 h2 __attribute__((ext_vector_type(2)));

#if defined(__has_builtin)
#if __has_builtin(__builtin_amdgcn_fdot2)
#define HAS_FDOT2 1
#endif
#endif

__device__ __forceinline__ u64 ld_a8(const float* p) {
  return __hip_atomic_load((const u64*)p, __ATOMIC_RELAXED,
                           __HIP_MEMORY_SCOPE_AGENT);
}
__device__ __forceinline__ void st_a4(float* p, float v) {
  __hip_atomic_store(p, v, __ATOMIC_RELAXED, __HIP_MEMORY_SCOPE_AGENT);
}
__device__ __forceinline__ bool fresh8(u64 v) {
  return ((u32)v != 0xFFFFFFFFu) & ((u32)(v >> 32) != 0xFFFFFFFFu);
}
__device__ __forceinline__ h2 pk2(float a, float b) {
  h2 r; r[0] = (_Float16)a; r[1] = (_Float16)b; return r;   // RNE converts
}
__device__ __forceinline__ float dot2(h2 a, h2 b, float c) {
#ifdef HAS_FDOT2
  return __builtin_amdgcn_fdot2(a, b, c, false);
#else
  return c + (float)a[0] * (float)b[0] + (float)a[1] * (float)b[1];
#endif
}
__device__ __forceinline__ float fast_tanh(float s) {
  float e = __expf(2.f * s);          // inf for large s -> 1; 0 -> -1
  return 1.f - 2.f / (e + 1.f);
}

__launch_bounds__(NTH, 2)
__global__ void rnn_d4(const float* __restrict__ x,
                       const float* __restrict__ w_ih,
                       const float* __restrict__ w_hh,
                       const float* __restrict__ b_ih,
                       const float* __restrict__ b_hh,
                       const float* __restrict__ w_fc,
                       const float* __restrict__ b_fc,
                       float* __restrict__ out,
                       float* ws)
{
  const int blk  = blockIdx.x;
  const int l    = blk >> 6;          // layer 0..3
  const int gb   = blk & (LBLK - 1);  // block within layer
  const int tid  = threadIdx.x;
  const int wid  = tid >> 6;
  const int lane = tid & 63;
  const int scol = wid * 256 + lane * 4;   // this lane's 4 columns

  float* outB      = ws + (size_t)l * (TT + 1) * HH;
  const float* inB = ws + (size_t)(l - 1) * (TT + 1) * HH;  // l>0 only

  __shared__ float partial[2][8][32];

  // ---- weights into VGPRs (once), f16-packed: [32][2] half2 each ----
  h2 whh[ROWS][2], wih[ROWS][2];
#pragma unroll
  for (int r = 0; r < ROWS; ++r) {
    const size_t rowoff = ((size_t)l * HH + gb * ROWS + r) * HH + scol;
    const float4 vh = *(const float4*)(w_hh + rowoff);
    whh[r][0] = pk2(vh.x, vh.y); whh[r][1] = pk2(vh.z, vh.w);
    const float4 vi = *(const float4*)(w_ih + rowoff);
    wih[r][0] = pk2(vi.x, vi.y); wih[r][1] = pk2(vi.z, vi.w);
  }
  float fbias = 0.f;
  if (wid == 0 && lane < 32)
    fbias = b_ih[l * HH + gb * ROWS + lane] + b_hh[l * HH + gb * ROWS + lane];

  // row this lane owns after the distributed reduce: bitrev5(lane&31)
  const int rrow = ((lane & 1) << 4) | ((lane & 2) << 2) | (lane & 4) |
                   ((lane & 8) >> 2) | ((lane & 16) >> 4);

  const float* po = outB + scol;            // own slot t (starts at t=0)
  const float* pp = inB + HH + scol;        // prev slot t+1
  float* ps = outB + HH + gb * ROWS + lane; // wave0 store ptr (slot t+1)
  const float* xb = x + (size_t)scol * TT;  // x[scol][t]

  for (int t = 0; t < TT; ++t) {
    // hoisted x gather (layer 0 only) — latency hides under the poll
    float xg0 = 0.f, xg1 = 0.f, xg2 = 0.f, xg3 = 0.f;
    if (l == 0) {
      xg0 = xb[0 * TT + t]; xg1 = xb[1 * TT + t];
      xg2 = xb[2 * TT + t]; xg3 = xb[3 * TT + t];
    }

    // ---- split sentinel poll ----
    // own h_{t-1} slice: produced a full step ago, almost always fresh ->
    // exits in ~1 iteration and stops generating traffic.
    u64 o0, o1, p0 = 0, p1 = 0;
    for (;;) {
      o0 = ld_a8(po);
      o1 = ld_a8(po + 2);
      if (__all(fresh8(o0) & fresh8(o1))) break;
      __builtin_amdgcn_s_sleep(8);
    }
    // prev-layer h_t slice: the fresh dependency; camp here only.
    if (l > 0) {
      for (;;) {
        p0 = ld_a8(pp);
        p1 = ld_a8(pp + 2);
        if (__all(fresh8(p0) & fresh8(p1))) break;
        __builtin_amdgcn_s_sleep(8);
      }
    }
    __syncthreads();   // lockstep barrier: block leaves poll phase together

    float hh0 = __uint_as_float((u32)o0), hh1 = __uint_as_float((u32)(o0 >> 32));
    float hh2 = __uint_as_float((u32)o1), hh3 = __uint_as_float((u32)(o1 >> 32));
    float hi0, hi1, hi2, hi3;
    if (l == 0) { hi0 = xg0; hi1 = xg1; hi2 = xg2; hi3 = xg3; }
    else {
      hi0 = __uint_as_float((u32)p0); hi1 = __uint_as_float((u32)(p0 >> 32));
      hi2 = __uint_as_float((u32)p1); hi3 = __uint_as_float((u32)(p1 >> 32));
    }
    const h2 ph0 = pk2(hh0, hh1), ph1 = pk2(hh2, hh3);
    const h2 pi0 = pk2(hi0, hi1), pi1 = pk2(hi2, hi3);

    // ---- per-lane partials: 32 rows x 4 cols, 4 fdot2/row ----
    float acc[ROWS];
#pragma unroll
    for (int r = 0; r < ROWS; ++r)
      acc[r] = dot2(whh[r][1], ph1,
               dot2(whh[r][0], ph0,
               dot2(wih[r][1], pi1,
               dot2(wih[r][0], pi0, 0.f))));

    // ---- distributed reduce: xor-32 pre-level, then 5 halving levels ----
#pragma unroll
    for (int i = 0; i < 32; ++i) acc[i] += __shfl_xor(acc[i], 32, 64);
#pragma unroll
    for (int lv = 0; lv < 5; ++lv) {
      const int m = 1 << lv;
      const int n = 16 >> lv;          // 16,8,4,2,1
      const bool up = (lane & m) != 0;
#pragma unroll
      for (int i = 0; i < 16; ++i) {
        if (i < n) {
          float mine   = up ? acc[i + n] : acc[i];
          float theirs = __shfl_xor(up ? acc[i] : acc[i + n], m, 64);
          acc[i] = mine + theirs;
        }
      }
    }
    if (lane < 32) partial[t & 1][wid][rrow] = acc[0];
    __syncthreads();                    // barrier2: partials ready

    if (wid == 0 && lane < 32) {
      float s = fbias;
#pragma unroll
      for (int w = 0; w < 8; ++w) s += partial[t & 1][w][lane];
      st_a4(ps, fast_tanh(s));
    }
    po += HH; pp += HH; ps += HH;
  }

  // ---- FC on h3[T-1]: layer-3 group only (weight regs are dead now) ----
  if (l == 3) {
    float wf[ROWS][4];
#pragma unroll
    for (int r = 0; r < ROWS; ++r) {
      const float4 v = *(const float4*)(w_fc + (size_t)(gb * ROWS + r) * HH + scol);
      wf[r][0] = v.x; wf[r][1] = v.y; wf[r][2] = v.z; wf[r][3] = v.w;
    }
    const float* ph = outB + (size_t)TT * HH + scol;
    u64 o0, o1;
    for (;;) {
      o0 = ld_a8(ph);
      o1 = ld_a8(ph + 2);
      if (__all(fresh8(o0) & fresh8(o1))) break;
      __builtin_amdgcn_s_sleep(8);
    }
    float h0 = __uint_as_float((u32)o0), h1 = __uint_as_float((u32)(o0 >> 32));
    float h2v = __uint_as_float((u32)o1), h3 = __uint_as_float((u32)(o1 >> 32));

    float acc[ROWS];
#pragma unroll
    for (int r = 0; r < ROWS; ++r)
      acc[r] = wf[r][0] * h0 + wf[r][1] * h1 + wf[r][2] * h2v + wf[r][3] * h3;
#pragma unroll
    for (int i = 0; i < 32; ++i) acc[i] += __shfl_xor(acc[i], 32, 64);
#pragma unroll
    for (int lv = 0; lv < 5; ++lv) {
      const int m = 1 << lv;
      const int n = 16 >> lv;
      const bool up = (lane & m) != 0;
#pragma unroll
      for (int i = 0; i < 16; ++i) {
        if (i < n) {
          float mine   = up ? acc[i + n] : acc[i];
          float theirs = __shfl_xor(up ? acc[i] : acc[i + n], m, 64);
          acc[i] = mine + theirs;
        }
      }
    }
    if (lane < 32) partial[0][wid][rrow] = acc[0];
    __syncthreads();
    if (wid == 0 && lane < 32) {
      float s = b_fc[gb * ROWS + lane];
#pragma unroll
      for (int w = 0; w < 8; ++w) s += partial[0][w][lane];
      out[gb * ROWS + lane] = s;
    }
  }
}

extern "C" void kernel_launch(void* const* d_in, const int* in_sizes, int n_in,
                              void* d_out, int out_size, void* d_ws, size_t ws_size,
                              hipStream_t stream) {
  const float* x    = (const float*)d_in[0];
  const float* w_ih = (const float*)d_in[1];
  const float* w_hh = (const float*)d_in[2];
  const float* b_ih = (const float*)d_in[3];
  const float* b_hh = (const float*)d_in[4];
  const float* w_fc = (const float*)d_in[5];
  const float* b_fc = (const float*)d_in[6];
  float* out = (float*)d_out;
  float* ws  = (float*)d_ws;

  // 4 exchange buffers (one per layer): (TT+1) x HH floats each.
  // Sentinel-fill, then zero slot 0 (= h_{-1}) of each.
  const size_t bufFloats = (size_t)(TT + 1) * HH;
  hipMemsetAsync(ws, 0xFF, 4 * bufFloats * sizeof(float), stream);
  for (int l = 0; l < 4; ++l)
    hipMemsetAsync(ws + l * bufFloats, 0, HH * sizeof(float), stream);

  rnn_d4<<<NBLK, NTH, 0, stream>>>(x, w_ih, w_hh, b_ih, b_hh,
                                   w_fc, b_fc, out, ws);
}